// Round 11
// baseline (361.230 us; speedup 1.0000x reference)
//
#include <hip/hip_runtime.h>
#include <hip/hip_bf16.h>

#define B_ 4
#define N_ 2048
#define C_ 1024
#define H_ 16
#define D_ 64
#define SCALE_ 0.125f

typedef _Float16 f16;
typedef __attribute__((ext_vector_type(8))) _Float16 f16x8;
typedef __attribute__((ext_vector_type(4))) _Float16 f16x4;
typedef __attribute__((ext_vector_type(4))) float f32x4;
typedef __attribute__((ext_vector_type(16))) float f32x16;
#define MFMA16(a, b, c) __builtin_amdgcn_mfma_f32_16x16x32_f16(a, b, c, 0, 0, 0)
#define MFMA32(a, b, c) __builtin_amdgcn_mfma_f32_32x32x16_f16(a, b, c, 0, 0, 0)

__device__ inline void gload_lds16(const f16* g, f16* l) {
    __builtin_amdgcn_global_load_lds(
        (const __attribute__((address_space(1))) void*)g,
        (__attribute__((address_space(3))) void*)l, 16, 0, 0);
}

// ---------------- f32 -> f16 convert (x, qkv_w, proj_w) ----------------
#define NX_ 8388608u
#define NW1_ 3145728u
#define NW2_ 1048576u

__global__ __launch_bounds__(256) void convert_kernel(
    const float* __restrict__ x, const float* __restrict__ w1, const float* __restrict__ w2,
    f16* __restrict__ xo, f16* __restrict__ w1o, f16* __restrict__ w2o)
{
    const unsigned q = blockIdx.x * 256 + threadIdx.x;
    const unsigned i = q << 2;
    const float* src;
    f16* dst;
    if (i < NX_)              { src = x  + i;               dst = xo  + i; }
    else if (i < NX_ + NW1_)  { src = w1 + (i - NX_);       dst = w1o + (i - NX_); }
    else                      { src = w2 + (i - NX_ - NW1_); dst = w2o + (i - NX_ - NW1_); }
    const float4 v = *(const float4*)src;
    f16x4 h;
    h[0] = (f16)v.x; h[1] = (f16)v.y; h[2] = (f16)v.z; h[3] = (f16)v.w;
    *(f16x4*)dst = h;
}

// ---------------- f16 MFMA GEMM: C[m][o] = sum_k A[m][k] * W[o][k] ----------------
__global__ __launch_bounds__(256) void qkv_gemm_f16(
    const f16* __restrict__ Xh,        // [8192][1024]
    const f16* __restrict__ Wh,        // [3072][1024]
    const float* __restrict__ qkv_b,
    const float* __restrict__ bias_mask,
    f16* __restrict__ Qh,              // [BH][N][D] (pre-scaled)
    f16* __restrict__ Kh,              // [BH][N][D]
    f16* __restrict__ Vt)              // [BH][D][N]
{
    __shared__ f16 As[128 * 64];
    __shared__ f16 Bs[128 * 64];
    const int tid  = threadIdx.x;
    const int bm   = blockIdx.x * 128;
    const int bo   = blockIdx.y * 128;
    const int lane = tid & 63, lo = lane & 15, grp = lane >> 4;
    const int wave = tid >> 6, wr = wave >> 1, wc = wave & 1;
    const int sr = tid >> 3, cg = tid & 7;
    const int scol = (cg ^ (sr & 7)) << 3;

    f32x4 acc[4][4];
    #pragma unroll
    for (int m = 0; m < 4; ++m)
        #pragma unroll
        for (int n = 0; n < 4; ++n) acc[m][n] = f32x4{0.f, 0.f, 0.f, 0.f};

    for (int k0 = 0; k0 < 1024; k0 += 64) {
        #pragma unroll
        for (int i = 0; i < 4; ++i) {
            const int tr = i * 32 + sr;
            gload_lds16(Xh + (size_t)(bm + tr) * 1024 + k0 + scol, As + (i * 2048 + tid * 8));
            gload_lds16(Wh + (size_t)(bo + tr) * 1024 + k0 + scol, Bs + (i * 2048 + tid * 8));
        }
        __syncthreads();
        #pragma unroll
        for (int kh = 0; kh < 2; ++kh) {
            f16x8 af[4], bfr[4];
            #pragma unroll
            for (int m = 0; m < 4; ++m) {
                const int row = wr * 64 + m * 16 + lo;
                af[m] = *(const f16x8*)(As + row * 64 + ((((kh << 2) + grp) << 3) ^ ((row & 7) << 3)));
            }
            #pragma unroll
            for (int n = 0; n < 4; ++n) {
                const int row = wc * 64 + n * 16 + lo;
                bfr[n] = *(const f16x8*)(Bs + row * 64 + ((((kh << 2) + grp) << 3) ^ ((row & 7) << 3)));
            }
            #pragma unroll
            for (int m = 0; m < 4; ++m)
                #pragma unroll
                for (int n = 0; n < 4; ++n)
                    acc[m][n] = MFMA16(af[m], bfr[n], acc[m][n]);
        }
        __syncthreads();
    }
    #pragma unroll
    for (int ni = 0; ni < 4; ++ni) {
        const int o = bo + wc * 64 + ni * 16 + lo;
        const float bias = qkv_b[o] * bias_mask[o];
        const int s = o >> 10, h = (o >> 6) & 15, d = o & 63;
        #pragma unroll
        for (int mi = 0; mi < 4; ++mi) {
            #pragma unroll
            for (int r = 0; r < 4; ++r) {
                const int m = bm + wr * 64 + mi * 16 + grp * 4 + r;
                const int b = m >> 11, n = m & (N_ - 1);
                const int bh = b * H_ + h;
                const float val = acc[mi][ni][r] + bias;
                if (s == 0)      Qh[((size_t)bh * N_ + n) * D_ + d] = (f16)(val * SCALE_);
                else if (s == 1) Kh[((size_t)bh * N_ + n) * D_ + d] = (f16)val;
                else             Vt[((size_t)bh * D_ + d) * N_ + n] = (f16)val;
            }
        }
    }
}

__global__ __launch_bounds__(256) void proj_gemm_f16(
    const f16* __restrict__ Ah,        // [8192][1024] attn out
    const f16* __restrict__ Wh,        // [1024][1024]
    const float* __restrict__ proj_b,
    float* __restrict__ Out)           // [8192][1024] f32
{
    __shared__ f16 As[128 * 64];
    __shared__ f16 Bs[128 * 64];
    const int tid  = threadIdx.x;
    const int bm   = blockIdx.x * 128;
    const int bo   = blockIdx.y * 128;
    const int lane = tid & 63, lo = lane & 15, grp = lane >> 4;
    const int wave = tid >> 6, wr = wave >> 1, wc = wave & 1;
    const int sr = tid >> 3, cg = tid & 7;
    const int scol = (cg ^ (sr & 7)) << 3;

    f32x4 acc[4][4];
    #pragma unroll
    for (int m = 0; m < 4; ++m)
        #pragma unroll
        for (int n = 0; n < 4; ++n) acc[m][n] = f32x4{0.f, 0.f, 0.f, 0.f};

    for (int k0 = 0; k0 < 1024; k0 += 64) {
        #pragma unroll
        for (int i = 0; i < 4; ++i) {
            const int tr = i * 32 + sr;
            gload_lds16(Ah + (size_t)(bm + tr) * 1024 + k0 + scol, As + (i * 2048 + tid * 8));
            gload_lds16(Wh + (size_t)(bo + tr) * 1024 + k0 + scol, Bs + (i * 2048 + tid * 8));
        }
        __syncthreads();
        #pragma unroll
        for (int kh = 0; kh < 2; ++kh) {
            f16x8 af[4], bfr[4];
            #pragma unroll
            for (int m = 0; m < 4; ++m) {
                const int row = wr * 64 + m * 16 + lo;
                af[m] = *(const f16x8*)(As + row * 64 + ((((kh << 2) + grp) << 3) ^ ((row & 7) << 3)));
            }
            #pragma unroll
            for (int n = 0; n < 4; ++n) {
                const int row = wc * 64 + n * 16 + lo;
                bfr[n] = *(const f16x8*)(Bs + row * 64 + ((((kh << 2) + grp) << 3) ^ ((row & 7) << 3)));
            }
            #pragma unroll
            for (int m = 0; m < 4; ++m)
                #pragma unroll
                for (int n = 0; n < 4; ++n)
                    acc[m][n] = MFMA16(af[m], bfr[n], acc[m][n]);
        }
        __syncthreads();
    }
    #pragma unroll
    for (int ni = 0; ni < 4; ++ni) {
        const int o = bo + wc * 64 + ni * 16 + lo;
        const float pb = proj_b[o];
        #pragma unroll
        for (int mi = 0; mi < 4; ++mi) {
            #pragma unroll
            for (int r = 0; r < 4; ++r) {
                const int m = bm + wr * 64 + mi * 16 + grp * 4 + r;
                Out[(size_t)m * C_ + o] = acc[mi][ni][r] + pb;
            }
        }
    }
}

// ---------------- pipelined swapped-QK^T 32x32 MFMA flash attention ----------------
// 2 chunks per iteration: S_B MFMA issued before softmax_A VALU (pipes overlap);
// K prefetched 2 half-chunks ahead, V 1 ahead; exact defer-rescale; tree reductions.
// Layouts as r10 (validated): S^T lane(lo,hi) reg r = S[kv=(r&3)+8(r>>2)+4hi][q=lo].

#define LDK(kv, r0, r1, r2, r3)                                              \
    { const f16* kr_ = Kp + (size_t)((kv) + lo) * D_ + hi * 8;               \
      r0 = *(const f16x8*)kr_;        r1 = *(const f16x8*)(kr_ + 16);        \
      r2 = *(const f16x8*)(kr_ + 32); r3 = *(const f16x8*)(kr_ + 48); }

#define LDV(kv, r0, r1, r2, r3)                                              \
    { const f16* vr_ = Vp + (size_t)lo * N_ + (kv) + hi * 8;                 \
      r0 = *(const f16x8*)vr_;  r1 = *(const f16x8*)(vr_ + 16);              \
      const f16* vr2_ = Vp + (size_t)(32 + lo) * N_ + (kv) + hi * 8;         \
      r2 = *(const f16x8*)vr2_; r3 = *(const f16x8*)(vr2_ + 16); }

#define SQK(sdst, k0_, k1_, k2_, k3_)                                        \
    sdst = MFMA32(k0_, qf0, zero16); sdst = MFMA32(k1_, qf1, sdst);          \
    sdst = MFMA32(k2_, qf2, sdst);   sdst = MFMA32(k3_, qf3, sdst);

#define SMAX_PV(S, V0, V1, V2, V3, PW)                                       \
  {                                                                          \
    float t01 = fmaxf(S[0], S[1]),  t23 = fmaxf(S[2], S[3]);                 \
    float t45 = fmaxf(S[4], S[5]),  t67 = fmaxf(S[6], S[7]);                 \
    float t89 = fmaxf(S[8], S[9]),  tab = fmaxf(S[10], S[11]);               \
    float tcd = fmaxf(S[12], S[13]), tef = fmaxf(S[14], S[15]);              \
    float tmax = fmaxf(fmaxf(fmaxf(t01, t23), fmaxf(t45, t67)),              \
                       fmaxf(fmaxf(t89, tab), fmaxf(tcd, tef)));             \
    tmax = fmaxf(tmax, __shfl_xor(tmax, 32, 64));                            \
    if (__any(tmax > m)) {                                                   \
      const float mn = fmaxf(m, tmax);                                       \
      const float corr = __expf(m - mn);                                     \
      m = mn; lsum *= corr;                                                  \
      _Pragma("unroll") for (int r = 0; r < 16; ++r) { o0[r] *= corr; o1[r] *= corr; } \
    }                                                                        \
    float p[16];                                                             \
    _Pragma("unroll") for (int r = 0; r < 16; ++r) p[r] = __expf(S[r] - m);  \
    float rs = (((p[0]+p[1])+(p[2]+p[3])) + ((p[4]+p[5])+(p[6]+p[7])))       \
             + (((p[8]+p[9])+(p[10]+p[11])) + ((p[12]+p[13])+(p[14]+p[15])));\
    rs += __shfl_xor(rs, 32, 64);                                            \
    lsum += rs;                                                              \
    _Pragma("unroll") for (int i = 0; i < 8; ++i) {                          \
      const int kvp = ((i & 1) << 1) + ((i >> 1) << 3) + (hi << 2);          \
      const f16 h0_ = (f16)p[2 * i];  const f16 h1_ = (f16)p[2 * i + 1];     \
      const unsigned w_ = (unsigned)__builtin_bit_cast(unsigned short, h0_) |\
                          ((unsigned)__builtin_bit_cast(unsigned short, h1_) << 16); \
      *(unsigned*)((PW) + lo * 36 + kvp) = w_;                               \
    }                                                                        \
    const f16x8 pb1_ = *(const f16x8*)((PW) + lo * 36 + hi * 8);             \
    const f16x8 pb2_ = *(const f16x8*)((PW) + lo * 36 + 16 + hi * 8);        \
    o0 = MFMA32(V0, pb1_, o0); o0 = MFMA32(V1, pb2_, o0);                    \
    o1 = MFMA32(V2, pb1_, o1); o1 = MFMA32(V3, pb2_, o1);                    \
  }

__global__ __launch_bounds__(256) void attn_fa4_kernel(
    const f16* __restrict__ Qb,  // [BH][N][D] (scaled)
    const f16* __restrict__ Kb,  // [BH][N][D]
    const f16* __restrict__ Vt,  // [BH][D][N]
    f16* __restrict__ AO)        // [B][N][C] f16
{
    __shared__ f16 Plds[4][2][32 * 36];   // per-wave A/B P tiles
    const int tid  = threadIdx.x;
    const int wave = tid >> 6;
    const int lane = tid & 63;
    const int lo   = lane & 31;
    const int hi   = lane >> 5;
    const int bh   = blockIdx.y;
    const int q0   = blockIdx.x * 128 + wave * 32;
    const size_t base = (size_t)bh * (N_ * D_);

    const f16* Qp = Qb + base + (size_t)(q0 + lo) * D_ + hi * 8;
    const f16x8 qf0 = *(const f16x8*)(Qp);
    const f16x8 qf1 = *(const f16x8*)(Qp + 16);
    const f16x8 qf2 = *(const f16x8*)(Qp + 32);
    const f16x8 qf3 = *(const f16x8*)(Qp + 48);

    const f32x16 zero16 = {};
    f32x16 o0 = zero16, o1 = zero16;
    float m = -1e30f, lsum = 0.f;
    const f16* Kp = Kb + base;
    const f16* Vp = Vt + base;
    f16* pwA = &Plds[wave][0][0];
    f16* pwB = &Plds[wave][1][0];

    f16x8 ka0, ka1, ka2, ka3, kb0, kb1, kb2, kb3;
    f16x8 va0, va1, va2, va3, vb0, vb1, vb2, vb3;

    LDK(0, ka0, ka1, ka2, ka3);  LDV(0, va0, va1, va2, va3);
    LDK(32, kb0, kb1, kb2, kb3); LDV(32, vb0, vb1, vb2, vb3);

    f32x16 sA, sB;
    SQK(sA, ka0, ka1, ka2, ka3);

    for (int t = 0; t < 32; ++t) {
        const int kvA = t * 64;
        const int nA = (t < 31) ? kvA + 64 : kvA;   // clamped prefetch (last-iter results unused)
        const int nB = (t < 31) ? kvA + 96 : kvA + 32;

        SQK(sB, kb0, kb1, kb2, kb3);                // chunk B scores — overlaps softmax A below
        LDK(nA, ka0, ka1, ka2, ka3);                // prefetch next A (covered by softmax A+B)
        LDK(nB, kb0, kb1, kb2, kb3);                // prefetch next B

        SMAX_PV(sA, va0, va1, va2, va3, pwA);       // softmax+PV chunk A (VALU ∥ sB MFMA)
        LDV(nA, va0, va1, va2, va3);

        SQK(sA, ka0, ka1, ka2, ka3);                // next A scores — overlaps softmax B
        SMAX_PV(sB, vb0, vb1, vb2, vb3, pwB);       // softmax+PV chunk B
        LDV(nB, vb0, vb1, vb2, vb3);
    }

    // epilogue: normalize, write f16 out (lane's q = lo is one row n)
    const int b = bh >> 4;
    const int h = bh & (H_ - 1);
    const float inv = 1.f / lsum;
    f16* outp = AO + ((size_t)(b * N_ + q0 + lo)) * C_ + h * D_;
    #pragma unroll
    for (int dh = 0; dh < 2; ++dh) {
        #pragma unroll
        for (int j = 0; j < 4; ++j) {
            const int d0 = dh * 32 + 8 * j + 4 * hi;
            f16x4 st;
            #pragma unroll
            for (int e = 0; e < 4; ++e) {
                const float v = (dh == 0 ? o0[4 * j + e] : o1[4 * j + e]) * inv;
                st[e] = (f16)v;
            }
            *(f16x4*)(outp + d0) = st;
        }
    }
}

extern "C" void kernel_launch(void* const* d_in, const int* in_sizes, int n_in,
                              void* d_out, int out_size, void* d_ws, size_t ws_size,
                              hipStream_t stream) {
    const float* x         = (const float*)d_in[0];
    const float* qkv_w     = (const float*)d_in[1];
    const float* qkv_b     = (const float*)d_in[2];
    const float* bias_mask = (const float*)d_in[3];
    const float* proj_w    = (const float*)d_in[4];
    const float* proj_b    = (const float*)d_in[5];
    float* out = (float*)d_out;

    const size_t NE = (size_t)B_ * H_ * N_ * D_;   // 8388608
    f16* Xh = (f16*)d_ws;
    f16* Wh = Xh + NE;              // 3145728
    f16* Ph = Wh + NW1_;            // 1048576
    f16* Qh = Ph + NW2_;
    f16* Kh = Qh + NE;
    f16* Vt = Kh + NE;
    f16* AOh = Vt + NE;

    dim3 blk(256);
    convert_kernel<<<12288, blk, 0, stream>>>(x, qkv_w, proj_w, Xh, Wh, Ph);
    qkv_gemm_f16<<<dim3(64, 24), blk, 0, stream>>>(Xh, Wh, qkv_b, bias_mask, Qh, Kh, Vt);
    attn_fa4_kernel<<<dim3(N_ / 128, B_ * H_), blk, 0, stream>>>(Qh, Kh, Vt, AOh);
    proj_gemm_f16<<<dim3(64, 8), blk, 0, stream>>>(AOh, Ph, proj_b, out);
}